// Round 8
// baseline (485.815 us; speedup 1.0000x reference)
//
#include <hip/hip_runtime.h>

#define N_NODES 50000
#define N_EDGES 800000
#define IN_FEAT 512
#define OUT_FEAT 128

#define M_STRIPES ((N_NODES + 63) / 64)              // 782 stripes of 64 rows
#define GEMM_BLOCKS (M_STRIPES * 2)                  // x2 n-halves = 1564
#define ROWPTR_BLOCKS ((N_NODES + 1 + 511) / 512)    // 98 blocks of 512 thr

// NUMERICS CONTRACT (R3 post-mortem): the harness's np reference is matched
// bit-for-bit through the multispike quantizer ONLY when fp32 accumulation
// order is strictly sequential (k-order in GEMM, edge-order in SPMM).
// Do NOT split accumulator chains. Zero-padding with w=0 is bit-exact.
//
// R5/R6 HARD RULE: no big register array held across a loop boundary
// alongside a 64-VGPR accumulator (spills). (Here acc is only 8 VGPR, so a
// 32-VGPR A prefetch is safe: ~80 total under launch_bounds(512,4).)
// R9: spmm is fabric-BW bound at ~3 TB/s on 410MB of irreducible gather
// traffic. spmm FROZEN.
// R4-R11 postmortem: every LDS-tiled fp32 GEMM variant walls at ~139us
// because LDS demand (0.25-0.375 read-floats/FMA through one 32-bank pipe
// + staging stores + conflicts) ~= the wall (R10: within 3%). R12 removes
// LDS from the GEMM entirely: wave = 64m x 8n, lane owns one m-row.
//   - B[k][n0..n0+7] is wave-uniform -> readfirstlane'd base, uniform
//     loads (scalar cache / L1 broadcast, NOT the LDS pipe); v_fma_f32
//     takes the one allowed SGPR operand.
//   - A streamed lane-private: 8 float4/chunk, contiguous 128B per lane
//     per chunk -> L1 lines fully consumed across kq; no staging at all.
//   - No barriers, no LDS, no bank conflicts in the GEMM.

__device__ __forceinline__ float multispike(float a) {
    // floor(clamp(4x, 0, 4) + 0.5) / 4
    return floorf(fminf(fmaxf(4.0f * a, 0.0f), 4.0f) + 0.5f) * 0.25f;
}

// ---------------------------------------------------------------------------
// GEMM: C[M,128] = A[M,512] @ B[512,128], fp32 vector FMA, ZERO LDS.
// Grid: bid = stripe*2 + n_half. Block 512 thr = 8 waves; wave w covers
// n-cols [n_half*64 + w*8, +8); all 8 waves share one 64-row m-stripe
// (A L1 reuse). Lane l owns row m = stripe*64 + l: acc[8] only.
// Per 32-k chunk: 8x float4 A (lane-private), per k one uniform 8-float
// B row-slice feeding 8 FMAs. k ascends 0..511 in order -> bit-exact.
// Blocks [GEMM_BLOCKS, +ROWPTR_BLOCKS): fused row_ptr binary search.
// ---------------------------------------------------------------------------
__global__ __launch_bounds__(512, 4) void gemm_rowptr_kernel(
    const float* __restrict__ A, const float* __restrict__ B,
    float* __restrict__ C, int M,
    const int* __restrict__ rows, int* __restrict__ row_ptr) {
    const int tid = threadIdx.x;

    if (blockIdx.x >= GEMM_BLOCKS) {
        // ---- fused rowptr: binary search, no LDS, no barriers.
        int i = (blockIdx.x - GEMM_BLOCKS) * 512 + tid;
        if (i <= N_NODES) {
            int lo = 0, hi = N_EDGES;
            while (lo < hi) {
                int mid = (lo + hi) >> 1;
                if (rows[mid] < i) lo = mid + 1; else hi = mid;
            }
            row_ptr[i] = lo;
        }
        return;
    }

    const int stripe = blockIdx.x >> 1;
    const int n_half = blockIdx.x & 1;
    const int wave = tid >> 6;
    const int lane = tid & 63;

    // wave-uniform n-base, pinned to an SGPR so B loads scalarize.
    const int n0 = __builtin_amdgcn_readfirstlane(n_half * 64 + wave * 8);
    const float* __restrict__ Bu = B + n0;

    const int gm = stripe * 64 + lane;
    const float* __restrict__ Arow =
        A + (size_t)(gm < M ? gm : M - 1) * IN_FEAT;   // clamp: never stored

    float acc[8];
#pragma unroll
    for (int j = 0; j < 8; j++) acc[j] = 0.0f;

    // A chunk registers: 8 x float4 = 32 k-values, lane-private.
    float4 a_cur[8];
#pragma unroll
    for (int i = 0; i < 8; i++) a_cur[i] = *(const float4*)(Arow + i * 4);

#pragma unroll 2
    for (int t = 0; t < 16; t++) {
        const int k0 = t * 32;
        // prefetch next chunk's A while this chunk computes (32 VGPR; safe
        // with acc=8). Loads issue here; consumed after the FMA block.
        float4 a_nxt[8];
        if (t < 15) {
#pragma unroll
            for (int i = 0; i < 8; i++)
                a_nxt[i] = *(const float4*)(Arow + k0 + 32 + i * 4);
        }

#pragma unroll
        for (int kq = 0; kq < 8; kq++) {
            const float4 av = a_cur[kq];
#pragma unroll
            for (int kk = 0; kk < 4; kk++) {
                const float a = (kk == 0) ? av.x : (kk == 1) ? av.y
                              : (kk == 2) ? av.z : av.w;
                const float* bp = Bu + (size_t)(k0 + kq * 4 + kk) * OUT_FEAT;
                // bp is wave-uniform: 8 consecutive scalar loads (merge to
                // s_load_dwordx8); each FMA reads b as its one SGPR operand.
#pragma unroll
                for (int j = 0; j < 8; j++)
                    acc[j] = fmaf(bp[j], a, acc[j]);   // strict k-order
            }
        }
#pragma unroll
        for (int i = 0; i < 8; i++) a_cur[i] = a_nxt[i];
    }

    if (gm < M) {
        float* cp = C + (size_t)gm * OUT_FEAT + n0;
        *(float4*)cp = make_float4(acc[0], acc[1], acc[2], acc[3]);
        *(float4*)(cp + 4) = make_float4(acc[4], acc[5], acc[6], acc[7]);
    }
}

// ---------------------------------------------------------------------------
// SPMM + multispike (FROZEN, R9): one wave per output row, lane l owns
// float2 l. 16-deep gather pipeline, zero-padded (w=0 slots are bit-exact
// no-ops), ONE strict e-order FMA chain per accumulator.
// ---------------------------------------------------------------------------
__global__ __launch_bounds__(256) void spmm_kernel(const float* __restrict__ x,
                                                   const int* __restrict__ cols,
                                                   const float* __restrict__ ew,
                                                   const int* __restrict__ row_ptr,
                                                   float* __restrict__ out) {
    const int wave = threadIdx.x >> 6;
    const int lane = threadIdx.x & 63;
    const int r = blockIdx.x * 4 + wave;
    if (r >= N_NODES) return;

    const int e0 = row_ptr[r];
    const int e1 = row_ptr[r + 1];
    const int niter = (e1 - e0 + 15) >> 4;   // zero-padded to multiple of 16
    const float2* __restrict__ x2 = (const float2*)x;

    float accx = 0.0f, accy = 0.0f;

    for (int t = 0; t < niter; t++) {
        const int base = e0 + t * 16;
        int c[16];
        float w[16];
#pragma unroll
        for (int j = 0; j < 16; j++) {
            int e = base + j;
            int ee = (e < e1) ? e : (e1 - 1);
            c[j] = cols[ee];
            w[j] = (e < e1) ? ew[ee] : 0.0f;
        }
        float2 v[16];
#pragma unroll
        for (int j = 0; j < 16; j++) {
            v[j] = x2[(size_t)c[j] * 64 + lane];
        }
#pragma unroll
        for (int j = 0; j < 16; j++) {   // strict e-order accumulation
            accx = fmaf(w[j], v[j].x, accx);
            accy = fmaf(w[j], v[j].y, accy);
        }
    }

    float2* out2 = (float2*)out;
    out2[(size_t)r * 64 + lane] = make_float2(multispike(accx), multispike(accy));
}

extern "C" void kernel_launch(void* const* d_in, const int* in_sizes, int n_in,
                              void* d_out, int out_size, void* d_ws, size_t ws_size,
                              hipStream_t stream) {
    const float* feat = (const float*)d_in[0];   // [50000, 512]
    const float* weight = (const float*)d_in[1]; // [512, 128]
    const int* rows = (const int*)d_in[2];       // [800000] sorted
    const int* cols = (const int*)d_in[3];       // [800000]
    const float* ew = (const float*)d_in[4];     // [800000]
    float* out = (float*)d_out;                  // [50000, 128]

    // Workspace layout: x [50000*128 f32] then row_ptr [50001 i32]
    float* x = (float*)d_ws;
    int* row_ptr = (int*)((char*)d_ws + (size_t)N_NODES * OUT_FEAT * sizeof(float));

    gemm_rowptr_kernel<<<GEMM_BLOCKS + ROWPTR_BLOCKS, 512, 0, stream>>>(
        feat, weight, x, N_NODES, rows, row_ptr);
    spmm_kernel<<<(N_NODES + 3) / 4, 256, 0, stream>>>(x, cols, ew, row_ptr, out);
}

// Round 9
// 368.299 us; speedup vs baseline: 1.3191x; 1.3191x over previous
//
#include <hip/hip_runtime.h>

#define N_NODES 50000
#define N_EDGES 800000
#define IN_FEAT 512
#define OUT_FEAT 128

#define GEMM_BLOCKS ((N_NODES + 63) / 64)            // 782 (BM=64)
#define ROWPTR_BLOCKS ((N_NODES + 1 + 127) / 128)    // 391 blocks of 128 thr

// NUMERICS CONTRACT (R3 post-mortem): the harness's np reference is matched
// bit-for-bit through the multispike quantizer ONLY when fp32 accumulation
// order is strictly sequential (k-order in GEMM, edge-order in SPMM).
// Do NOT split accumulator chains (no split-K, no atomics, no reassoc).
// Zero-padding with w=0 is bit-exact.
//
// LEDGER (gemm structures, measured):
//   R4  BM=64 2-barrier BK=32 8x8 tile ............ 140.9us  <- baseline
//   R5  +reg prefetch across loop ................. 184    (spill)
//   R6  A-direct + DMA-B dbuf ..................... 225    (spill)
//   R7  full DMA dbuf, 1 barrier, 48KB ............ 180    (drain at barrier)
//   R10 BM=32 4x8, 12 waves/CU .................... 139.5  (LDS-saturated)
//   R11 1-wave blocks ............................. 197    (no TLP)
//   R12 zero-LDS scalar-B ......................... 324    (serialized B)
// R5/R6 HARD RULE: no multi-float4 register array held across a loop
// boundary alongside the accumulators (spills).
// R9: spmm is fabric/miss-queue bound at ~3 TB/s on 410MB of irreducible
// gather traffic (16-deep MLP probe neutral). spmm FROZEN.
// R13: R4's wall has ~10k cyc/chunk of per-barrier-period overhead
// (stage->L3 latency->drain serialized once per chunk; un-hideable within
// a block per R5-R7). BK 32->64 halves the barrier periods; LDS 25->49KB
// is free because the grid (782 blocks) caps us at 3 blocks/CU anyway.

__device__ __forceinline__ float multispike(float a) {
    // floor(clamp(4x, 0, 4) + 0.5) / 4
    return floorf(fminf(fmaxf(4.0f * a, 0.0f), 4.0f) + 0.5f) * 0.25f;
}

// ---------------------------------------------------------------------------
// GEMM: C[M,128] = A[M,512] @ B[512,128], fp32 vector FMA.
// BM=64, BN=128, BK=64. 128 threads (2 waves). Thread tile 8x8.
// Blocks [0, GEMM_BLOCKS): gemm. [GEMM_BLOCKS, +ROWPTR_BLOCKS): fused
// row_ptr binary search (no LDS, no barriers, exits early -> no hazard).
// - As[64][68]: transposed store, pad 68 keeps rows 16B-aligned for b128
//   reads; 4-way store conflict (R4-measured acceptable).
// - Bs XOR quad-swizzle bswz(q)=q^((q>>3)&1) on store and load (R4-
//   verified: makes the 128B-stride read aliasing 2-way = free, m136).
// - Inner k-loop kept as 2x32 so code size stays at R4's I-cache footprint.
// - Per-(m,n) fmaf chain: chunks ascend, k-in-chunk ascends -> k=0..511
//   strictly ascending -> bit-exact.
// ---------------------------------------------------------------------------
__device__ __forceinline__ int bswz(int q) { return q ^ ((q >> 3) & 1); }

__global__ __launch_bounds__(128) void gemm_rowptr_kernel(
    const float* __restrict__ A, const float* __restrict__ B,
    float* __restrict__ C, int M,
    const int* __restrict__ rows, int* __restrict__ row_ptr) {
    __shared__ float As[64][68];    // [k][m], padded        (17408 B)
    __shared__ float Bs[64][128];   // [k][n], quad-swizzled (32768 B)

    const int tid = threadIdx.x;

    if (blockIdx.x >= GEMM_BLOCKS) {
        // ---- fused rowptr: binary search, no LDS, no barriers.
        int i = (blockIdx.x - GEMM_BLOCKS) * 128 + tid;
        if (i <= N_NODES) {
            int lo = 0, hi = N_EDGES;
            while (lo < hi) {
                int mid = (lo + hi) >> 1;
                if (rows[mid] < i) lo = mid + 1; else hi = mid;
            }
            row_ptr[i] = lo;
        }
        return;
    }

    const int tx = tid & 15;   // n0 = tx*8
    const int ty = tid >> 4;   // m0 = ty*8 (0..7)
    const int block_m = blockIdx.x * 64;

    const int bq0 = bswz(2 * tx) * 4;
    const int bq1 = bswz(2 * tx + 1) * 4;

    float acc[8][8];
#pragma unroll
    for (int i = 0; i < 8; i++)
#pragma unroll
        for (int j = 0; j < 8; j++) acc[i][j] = 0.0f;

    for (int k0 = 0; k0 < IN_FEAT; k0 += 64) {
        // Stage A tile: 64 rows x 64 k = 1024 float4 / 128 threads = 8 each.
        // f -> row r = f>>4, quad q = f&15 (16 quads per 64-k row).
#pragma unroll
        for (int i = 0; i < 8; i++) {
            int f = tid + i * 128;
            int r = f >> 4;
            int kq = (f & 15) << 2;
            int gm = block_m + r;
            float4 v = make_float4(0.f, 0.f, 0.f, 0.f);
            if (gm < M) v = *(const float4*)(A + (size_t)gm * IN_FEAT + k0 + kq);
            As[kq + 0][r] = v.x;
            As[kq + 1][r] = v.y;
            As[kq + 2][r] = v.z;
            As[kq + 3][r] = v.w;
        }
        // Stage B tile: 64 rows x 128 n = 2048 float4 / 128 threads = 16 each.
#pragma unroll
        for (int i = 0; i < 16; i++) {
            int f = tid + i * 128;
            int r = f >> 5;             // 0..63
            int q = f & 31;
            *(float4*)&Bs[r][bswz(q) * 4] =
                *(const float4*)(B + (size_t)(k0 + r) * OUT_FEAT + q * 4);
        }
        __syncthreads();

        for (int kh = 0; kh < 2; kh++) {   // keep unrolled body at R4 size
#pragma unroll
            for (int kl = 0; kl < 32; kl++) {
                const int k = kh * 32 + kl;
                float4 a0 = *(const float4*)&As[k][ty * 8];
                float4 a1 = *(const float4*)&As[k][ty * 8 + 4];
                float4 b0 = *(const float4*)&Bs[k][bq0];
                float4 b1 = *(const float4*)&Bs[k][bq1];
                float av[8] = {a0.x, a0.y, a0.z, a0.w, a1.x, a1.y, a1.z, a1.w};
                float bv[8] = {b0.x, b0.y, b0.z, b0.w, b1.x, b1.y, b1.z, b1.w};
#pragma unroll
                for (int i = 0; i < 8; i++)
#pragma unroll
                    for (int j = 0; j < 8; j++)
                        acc[i][j] = fmaf(av[i], bv[j], acc[i][j]);
            }
        }
        __syncthreads();
    }

#pragma unroll
    for (int i = 0; i < 8; i++) {
        int gm = block_m + ty * 8 + i;
        if (gm < M) {
            float* cp = C + (size_t)gm * OUT_FEAT + tx * 8;
            *(float4*)cp = make_float4(acc[i][0], acc[i][1], acc[i][2], acc[i][3]);
            *(float4*)(cp + 4) = make_float4(acc[i][4], acc[i][5], acc[i][6], acc[i][7]);
        }
    }
}

// ---------------------------------------------------------------------------
// SPMM + multispike (FROZEN, R9): one wave per output row, lane l owns
// float2 l. 16-deep gather pipeline, zero-padded (w=0 slots are bit-exact
// no-ops), ONE strict e-order FMA chain per accumulator.
// ---------------------------------------------------------------------------
__global__ __launch_bounds__(256) void spmm_kernel(const float* __restrict__ x,
                                                   const int* __restrict__ cols,
                                                   const float* __restrict__ ew,
                                                   const int* __restrict__ row_ptr,
                                                   float* __restrict__ out) {
    const int wave = threadIdx.x >> 6;
    const int lane = threadIdx.x & 63;
    const int r = blockIdx.x * 4 + wave;
    if (r >= N_NODES) return;

    const int e0 = row_ptr[r];
    const int e1 = row_ptr[r + 1];
    const int niter = (e1 - e0 + 15) >> 4;   // zero-padded to multiple of 16
    const float2* __restrict__ x2 = (const float2*)x;

    float accx = 0.0f, accy = 0.0f;

    for (int t = 0; t < niter; t++) {
        const int base = e0 + t * 16;
        int c[16];
        float w[16];
#pragma unroll
        for (int j = 0; j < 16; j++) {
            int e = base + j;
            int ee = (e < e1) ? e : (e1 - 1);
            c[j] = cols[ee];
            w[j] = (e < e1) ? ew[ee] : 0.0f;
        }
        float2 v[16];
#pragma unroll
        for (int j = 0; j < 16; j++) {
            v[j] = x2[(size_t)c[j] * 64 + lane];
        }
#pragma unroll
        for (int j = 0; j < 16; j++) {   // strict e-order accumulation
            accx = fmaf(w[j], v[j].x, accx);
            accy = fmaf(w[j], v[j].y, accy);
        }
    }

    float2* out2 = (float2*)out;
    out2[(size_t)r * 64 + lane] = make_float2(multispike(accx), multispike(accy));
}

extern "C" void kernel_launch(void* const* d_in, const int* in_sizes, int n_in,
                              void* d_out, int out_size, void* d_ws, size_t ws_size,
                              hipStream_t stream) {
    const float* feat = (const float*)d_in[0];   // [50000, 512]
    const float* weight = (const float*)d_in[1]; // [512, 128]
    const int* rows = (const int*)d_in[2];       // [800000] sorted
    const int* cols = (const int*)d_in[3];       // [800000]
    const float* ew = (const float*)d_in[4];     // [800000]
    float* out = (float*)d_out;                  // [50000, 128]

    // Workspace layout: x [50000*128 f32] then row_ptr [50001 i32]
    float* x = (float*)d_ws;
    int* row_ptr = (int*)((char*)d_ws + (size_t)N_NODES * OUT_FEAT * sizeof(float));

    gemm_rowptr_kernel<<<GEMM_BLOCKS + ROWPTR_BLOCKS, 128, 0, stream>>>(
        feat, weight, x, N_NODES, rows, row_ptr);
    spmm_kernel<<<(N_NODES + 3) / 4, 256, 0, stream>>>(x, cols, ew, row_ptr, out);
}

// Round 10
// 358.139 us; speedup vs baseline: 1.3565x; 1.0284x over previous
//
#include <hip/hip_runtime.h>

#define N_NODES 50000
#define N_EDGES 800000
#define IN_FEAT 512
#define OUT_FEAT 128

#define GEMM_BLOCKS ((N_NODES + 31) / 32)            // 1563 (BM=32)
#define ROWPTR_BLOCKS ((N_NODES + 1 + 127) / 128)    // 391 blocks of 128 thr

// NUMERICS CONTRACT (R3 post-mortem): the harness's np reference is matched
// bit-for-bit through the multispike quantizer ONLY when fp32 accumulation
// order is strictly sequential (k-order in GEMM, edge-order in SPMM).
// Do NOT split accumulator chains (no split-K, no atomics, no reassoc).
// Zero-padding with w=0 is bit-exact.
//
// LEDGER (gemm structures, measured):
//   R4  BM=64 2-barrier BK=32 8x8, LDS A+B ........ 140.9us
//   R5  +reg prefetch across loop ................. 184    (spill)
//   R6  A-direct 8x8 + DMA-B dbuf ................. 225    (spill: acc64+arrays)
//   R7  full DMA dbuf, 1 barrier, 48KB ............ 180    (drain at barrier)
//   R10 BM=32 4x8, 12.2 waves/CU, LDS A+B ......... 139.5  (LDS-saturated)
//   R11 1-wave blocks ............................. 197    (no TLP)
//   R12 zero-LDS scalar-B ......................... 324    (serialized B)
//   R13 BK=64 .................................... 197    (longer bursts)
// R14: the unexplored cell = 12.2 waves/CU (R10's TLP) x A-direct-from-L1
// (kills the ~50us A-staging share of the saturated LDS pipe). 4x8 tile
// keeps acc=32 so the per-kq a[4] stays transient (~70-90 VGPR, no R5/R6
// spill). launch_bounds(128,3) caps VGPR at 170 and targets 6 blocks/CU.
// R9: spmm is fabric/miss-queue bound at ~3 TB/s on 410MB of irreducible
// gather traffic (16-deep MLP probe neutral). spmm FROZEN.

__device__ __forceinline__ float multispike(float a) {
    // floor(clamp(4x, 0, 4) + 0.5) / 4
    return floorf(fminf(fmaxf(4.0f * a, 0.0f), 4.0f) + 0.5f) * 0.25f;
}

// ---------------------------------------------------------------------------
// GEMM: C[M,128] = A[M,512] @ B[512,128], fp32 vector FMA.
// BM=32, BN=128, BK=32. 128 threads (2 waves). Thread tile 4x8.
// A: NO LDS -- each thread reads its 4 rows' float4 per kq straight from
//    global. The 16 same-ty lanes read the SAME address -> coalesced
//    broadcast, 64B/instr, served by L1 (4KB stripe/chunk, 16x reuse).
// B: LDS with the R4-verified XOR quad-swizzle (store+load same map,
//    2-way = free). Staged 8 float4/thread, 2-barrier cadence.
// Per-(m,n) fmaf chain: chunk asc, kq asc, kk asc -> k=0..511 strictly
// ascending -> bit-exact.
// Blocks [GEMM_BLOCKS, +ROWPTR_BLOCKS): fused row_ptr binary search.
// ---------------------------------------------------------------------------
__device__ __forceinline__ int bswz(int q) { return q ^ ((q >> 3) & 1); }

__global__ __launch_bounds__(128, 3) void gemm_rowptr_kernel(
    const float* __restrict__ A, const float* __restrict__ B,
    float* __restrict__ C, int M,
    const int* __restrict__ rows, int* __restrict__ row_ptr) {
    __shared__ float Bs[32][128];   // [k][n], quad-swizzled (16384 B)

    const int tid = threadIdx.x;

    if (blockIdx.x >= GEMM_BLOCKS) {
        // ---- fused rowptr: binary search, no LDS, no barriers.
        int i = (blockIdx.x - GEMM_BLOCKS) * 128 + tid;
        if (i <= N_NODES) {
            int lo = 0, hi = N_EDGES;
            while (lo < hi) {
                int mid = (lo + hi) >> 1;
                if (rows[mid] < i) lo = mid + 1; else hi = mid;
            }
            row_ptr[i] = lo;
        }
        return;
    }

    const int tx = tid & 15;   // n0 = tx*8
    const int ty = tid >> 4;   // 0..7, m0 = ty*4
    const int block_m = blockIdx.x * 32;

    const int bq0 = bswz(2 * tx) * 4;
    const int bq1 = bswz(2 * tx + 1) * 4;

    // Per-row A pointers, OOB-clamped (clamped rows are never stored).
    const float* arow[4];
#pragma unroll
    for (int i = 0; i < 4; i++) {
        int gm = block_m + ty * 4 + i;
        arow[i] = A + (size_t)(gm < M ? gm : M - 1) * IN_FEAT;
    }

    float acc[4][8];
#pragma unroll
    for (int i = 0; i < 4; i++)
#pragma unroll
        for (int j = 0; j < 8; j++) acc[i][j] = 0.0f;

    for (int k0 = 0; k0 < IN_FEAT; k0 += 32) {
        // Stage B tile only: 32 rows x 128 n = 1024 float4 / 128 thr = 8 each.
#pragma unroll
        for (int i = 0; i < 8; i++) {
            int f = tid + i * 128;
            int r = f >> 5;             // 0..31
            int q = f & 31;
            *(float4*)&Bs[r][bswz(q) * 4] =
                *(const float4*)(B + (size_t)(k0 + r) * OUT_FEAT + q * 4);
        }
        __syncthreads();

#pragma unroll
        for (int kq = 0; kq < 8; kq++) {
            // 4 lane-private (16-lane-broadcast) A loads; transient regs.
            float4 a[4];
#pragma unroll
            for (int i = 0; i < 4; i++)
                a[i] = *(const float4*)(arow[i] + k0 + kq * 4);
#pragma unroll
            for (int kk = 0; kk < 4; kk++) {
                const int k = kq * 4 + kk;
                float4 b0 = *(const float4*)&Bs[k][bq0];
                float4 b1 = *(const float4*)&Bs[k][bq1];
                float bv[8] = {b0.x, b0.y, b0.z, b0.w, b1.x, b1.y, b1.z, b1.w};
                float av[4];
#pragma unroll
                for (int i = 0; i < 4; i++)   // kk is compile-time constant
                    av[i] = (kk == 0) ? a[i].x : (kk == 1) ? a[i].y
                          : (kk == 2) ? a[i].z : a[i].w;
#pragma unroll
                for (int i = 0; i < 4; i++)
#pragma unroll
                    for (int j = 0; j < 8; j++)
                        acc[i][j] = fmaf(av[i], bv[j], acc[i][j]);
            }
        }
        __syncthreads();   // guards Bs overwrite next chunk
    }

#pragma unroll
    for (int i = 0; i < 4; i++) {
        int gm = block_m + ty * 4 + i;
        if (gm < M) {
            float* cp = C + (size_t)gm * OUT_FEAT + tx * 8;
            *(float4*)cp = make_float4(acc[i][0], acc[i][1], acc[i][2], acc[i][3]);
            *(float4*)(cp + 4) = make_float4(acc[i][4], acc[i][5], acc[i][6], acc[i][7]);
        }
    }
}

// ---------------------------------------------------------------------------
// SPMM + multispike (FROZEN, R9): one wave per output row, lane l owns
// float2 l. 16-deep gather pipeline, zero-padded (w=0 slots are bit-exact
// no-ops), ONE strict e-order FMA chain per accumulator.
// ---------------------------------------------------------------------------
__global__ __launch_bounds__(256) void spmm_kernel(const float* __restrict__ x,
                                                   const int* __restrict__ cols,
                                                   const float* __restrict__ ew,
                                                   const int* __restrict__ row_ptr,
                                                   float* __restrict__ out) {
    const int wave = threadIdx.x >> 6;
    const int lane = threadIdx.x & 63;
    const int r = blockIdx.x * 4 + wave;
    if (r >= N_NODES) return;

    const int e0 = row_ptr[r];
    const int e1 = row_ptr[r + 1];
    const int niter = (e1 - e0 + 15) >> 4;   // zero-padded to multiple of 16
    const float2* __restrict__ x2 = (const float2*)x;

    float accx = 0.0f, accy = 0.0f;

    for (int t = 0; t < niter; t++) {
        const int base = e0 + t * 16;
        int c[16];
        float w[16];
#pragma unroll
        for (int j = 0; j < 16; j++) {
            int e = base + j;
            int ee = (e < e1) ? e : (e1 - 1);
            c[j] = cols[ee];
            w[j] = (e < e1) ? ew[ee] : 0.0f;
        }
        float2 v[16];
#pragma unroll
        for (int j = 0; j < 16; j++) {
            v[j] = x2[(size_t)c[j] * 64 + lane];
        }
#pragma unroll
        for (int j = 0; j < 16; j++) {   // strict e-order accumulation
            accx = fmaf(w[j], v[j].x, accx);
            accy = fmaf(w[j], v[j].y, accy);
        }
    }

    float2* out2 = (float2*)out;
    out2[(size_t)r * 64 + lane] = make_float2(multispike(accx), multispike(accy));
}

extern "C" void kernel_launch(void* const* d_in, const int* in_sizes, int n_in,
                              void* d_out, int out_size, void* d_ws, size_t ws_size,
                              hipStream_t stream) {
    const float* feat = (const float*)d_in[0];   // [50000, 512]
    const float* weight = (const float*)d_in[1]; // [512, 128]
    const int* rows = (const int*)d_in[2];       // [800000] sorted
    const int* cols = (const int*)d_in[3];       // [800000]
    const float* ew = (const float*)d_in[4];     // [800000]
    float* out = (float*)d_out;                  // [50000, 128]

    // Workspace layout: x [50000*128 f32] then row_ptr [50001 i32]
    float* x = (float*)d_ws;
    int* row_ptr = (int*)((char*)d_ws + (size_t)N_NODES * OUT_FEAT * sizeof(float));

    gemm_rowptr_kernel<<<GEMM_BLOCKS + ROWPTR_BLOCKS, 128, 0, stream>>>(
        feat, weight, x, N_NODES, rows, row_ptr);
    spmm_kernel<<<(N_NODES + 3) / 4, 256, 0, stream>>>(x, cols, ew, row_ptr, out);
}

// Round 11
// 309.860 us; speedup vs baseline: 1.5679x; 1.1558x over previous
//
#include <hip/hip_runtime.h>

#define N_NODES 50000
#define N_EDGES 800000
#define IN_FEAT 512
#define OUT_FEAT 128

#define GEMM_BLOCKS ((N_NODES + 31) / 32)            // 1563 (BM=32)
#define ROWPTR_BLOCKS ((N_NODES + 1 + 127) / 128)    // 391 blocks of 128 thr

// NUMERICS CONTRACT (R3 post-mortem): the harness's np reference is matched
// bit-for-bit through the multispike quantizer ONLY when fp32 accumulation
// order is strictly sequential (k-order in GEMM, edge-order in SPMM).
// Do NOT split accumulator chains (no split-K, no atomics, no reassoc).
// Zero-padding with w=0 is bit-exact.
//
// FINAL LEDGER (gemm structures, measured):
//   R4  BM=64 2-barrier BK=32 8x8, LDS A+B ........ 140.9us  (latency-exposed)
//   R5  +reg prefetch across loop ................. 184      (spill)
//   R6  A-direct 8x8 + DMA-B dbuf ................. 225      (spill)
//   R7  full DMA dbuf, 1 barrier, 48KB ............ 180      (drain + 2 blk/CU)
//   R10 BM=32 4x8, high TLP, LDS A+B .............. 139.5 <- BEST (LDS-saturated)
//   R11 1-wave blocks ............................. 197      (no TLP)
//   R12 zero-LDS scalar-B ......................... 324      (serialized B)
//   R13 BK=64 ..................................... 197      (longer bursts)
//   R14 A-direct-from-L1 4x8, 31% occ ............. 184      (A-load serialization)
// Conclusion: fixed work => waves/CU x per-thread-tile conserved; 8x8 tile
// minimizes LDS reads but caps TLP at 1.5 waves/SIMD (exposed latency);
// 4x8 doubles TLP but re-saturates the LDS pipe (demand == wall within 3%).
// All staging alternatives lose to load-serialization or spill. VALU-busy
// has been invariant 47-51us (vs 41.7us fp32 floor) across ALL variants.
// MFMA barred by numerics (no fp32-input MFMA on CDNA4; casting changes
// quantizer inputs). gemm ~139.5us is the structural wall.
// R9: spmm is fabric/miss-queue bound at ~3 TB/s on 410MB of irreducible
// random gathers (16-deep MLP probe neutral). spmm ~135us is its wall.
// This file == the measured-best round-6 configuration (311.5us e2e).

__device__ __forceinline__ float multispike(float a) {
    // floor(clamp(4x, 0, 4) + 0.5) / 4
    return floorf(fminf(fmaxf(4.0f * a, 0.0f), 4.0f) + 0.5f) * 0.25f;
}

// ---------------------------------------------------------------------------
// GEMM: C[M,128] = A[M,512] @ B[512,128], fp32 vector FMA.
// BM=32, BN=128, BK=32. 128 threads (2 waves). Thread tile 4x8.
// Blocks [0, GEMM_BLOCKS): gemm. [GEMM_BLOCKS, +ROWPTR_BLOCKS): fused
// row_ptr binary search (no LDS, no barriers, exits early -> no hazard).
// - As[32][36]: transposed store, pad 36 keeps rows 16B-aligned for b128
//   reads; store conflict 4-way (measured acceptable).
// - A-read: ty*4 offsets {0,4,8,12} floats across wave -> 4 distinct bank
//   quads, conflict-free, 16-lane broadcast.
// - Bs XOR quad-swizzle bswz(q)=q^((q>>3)&1) on store and load: makes the
//   128B-stride read aliasing 2-way = time-free (m136).
// - Per-(m,n) fmaf chain runs k=0..511 strictly ascending -> bit-exact.
// ---------------------------------------------------------------------------
__device__ __forceinline__ int bswz(int q) { return q ^ ((q >> 3) & 1); }

__global__ __launch_bounds__(128) void gemm_rowptr_kernel(
    const float* __restrict__ A, const float* __restrict__ B,
    float* __restrict__ C, int M,
    const int* __restrict__ rows, int* __restrict__ row_ptr) {
    __shared__ float As[32][36];    // [k][m], padded
    __shared__ float Bs[32][128];   // [k][n], quad-swizzled

    const int tid = threadIdx.x;

    if (blockIdx.x >= GEMM_BLOCKS) {
        // ---- fused rowptr: binary search, no LDS, no barriers.
        int i = (blockIdx.x - GEMM_BLOCKS) * 128 + tid;
        if (i <= N_NODES) {
            int lo = 0, hi = N_EDGES;
            while (lo < hi) {
                int mid = (lo + hi) >> 1;
                if (rows[mid] < i) lo = mid + 1; else hi = mid;
            }
            row_ptr[i] = lo;
        }
        return;
    }

    const int tx = tid & 15;   // n0 = tx*8
    const int ty = tid >> 4;   // 0..7, m0 = ty*4
    const int block_m = blockIdx.x * 32;

    const int bq0 = bswz(2 * tx) * 4;
    const int bq1 = bswz(2 * tx + 1) * 4;

    float acc[4][8];
#pragma unroll
    for (int i = 0; i < 4; i++)
#pragma unroll
        for (int j = 0; j < 8; j++) acc[i][j] = 0.0f;

    for (int k0 = 0; k0 < IN_FEAT; k0 += 32) {
        // Stage A tile: 32 rows x 32 k = 256 float4 / 128 threads = 2 each.
#pragma unroll
        for (int i = 0; i < 2; i++) {
            int f = tid + i * 128;
            int r = f >> 3;             // 0..31
            int kq = (f & 7) << 2;
            int gm = block_m + r;
            float4 v = make_float4(0.f, 0.f, 0.f, 0.f);
            if (gm < M) v = *(const float4*)(A + (size_t)gm * IN_FEAT + k0 + kq);
            As[kq + 0][r] = v.x;
            As[kq + 1][r] = v.y;
            As[kq + 2][r] = v.z;
            As[kq + 3][r] = v.w;
        }
        // Stage B tile: 32 rows x 128 n = 1024 float4 / 128 threads = 8 each.
#pragma unroll
        for (int i = 0; i < 8; i++) {
            int f = tid + i * 128;
            int r = f >> 5;
            int q = f & 31;
            *(float4*)&Bs[r][bswz(q) * 4] =
                *(const float4*)(B + (size_t)(k0 + r) * OUT_FEAT + q * 4);
        }
        __syncthreads();

#pragma unroll
        for (int k = 0; k < 32; k++) {
            float4 a0 = *(const float4*)&As[k][ty * 4];
            float4 b0 = *(const float4*)&Bs[k][bq0];
            float4 b1 = *(const float4*)&Bs[k][bq1];
            float av[4] = {a0.x, a0.y, a0.z, a0.w};
            float bv[8] = {b0.x, b0.y, b0.z, b0.w, b1.x, b1.y, b1.z, b1.w};
#pragma unroll
            for (int i = 0; i < 4; i++)
#pragma unroll
                for (int j = 0; j < 8; j++)
                    acc[i][j] = fmaf(av[i], bv[j], acc[i][j]);
        }
        __syncthreads();
    }

#pragma unroll
    for (int i = 0; i < 4; i++) {
        int gm = block_m + ty * 4 + i;
        if (gm < M) {
            float* cp = C + (size_t)gm * OUT_FEAT + tx * 8;
            *(float4*)cp = make_float4(acc[i][0], acc[i][1], acc[i][2], acc[i][3]);
            *(float4*)(cp + 4) = make_float4(acc[i][4], acc[i][5], acc[i][6], acc[i][7]);
        }
    }
}

// ---------------------------------------------------------------------------
// SPMM + multispike (FROZEN, R9): one wave per output row, lane l owns
// float2 l. 16-deep gather pipeline, zero-padded (w=0 slots are bit-exact
// no-ops), ONE strict e-order FMA chain per accumulator.
// ---------------------------------------------------------------------------
__global__ __launch_bounds__(256) void spmm_kernel(const float* __restrict__ x,
                                                   const int* __restrict__ cols,
                                                   const float* __restrict__ ew,
                                                   const int* __restrict__ row_ptr,
                                                   float* __restrict__ out) {
    const int wave = threadIdx.x >> 6;
    const int lane = threadIdx.x & 63;
    const int r = blockIdx.x * 4 + wave;
    if (r >= N_NODES) return;

    const int e0 = row_ptr[r];
    const int e1 = row_ptr[r + 1];
    const int niter = (e1 - e0 + 15) >> 4;   // zero-padded to multiple of 16
    const float2* __restrict__ x2 = (const float2*)x;

    float accx = 0.0f, accy = 0.0f;

    for (int t = 0; t < niter; t++) {
        const int base = e0 + t * 16;
        int c[16];
        float w[16];
#pragma unroll
        for (int j = 0; j < 16; j++) {
            int e = base + j;
            int ee = (e < e1) ? e : (e1 - 1);
            c[j] = cols[ee];
            w[j] = (e < e1) ? ew[ee] : 0.0f;
        }
        float2 v[16];
#pragma unroll
        for (int j = 0; j < 16; j++) {
            v[j] = x2[(size_t)c[j] * 64 + lane];
        }
#pragma unroll
        for (int j = 0; j < 16; j++) {   // strict e-order accumulation
            accx = fmaf(w[j], v[j].x, accx);
            accy = fmaf(w[j], v[j].y, accy);
        }
    }

    float2* out2 = (float2*)out;
    out2[(size_t)r * 64 + lane] = make_float2(multispike(accx), multispike(accy));
}

extern "C" void kernel_launch(void* const* d_in, const int* in_sizes, int n_in,
                              void* d_out, int out_size, void* d_ws, size_t ws_size,
                              hipStream_t stream) {
    const float* feat = (const float*)d_in[0];   // [50000, 512]
    const float* weight = (const float*)d_in[1]; // [512, 128]
    const int* rows = (const int*)d_in[2];       // [800000] sorted
    const int* cols = (const int*)d_in[3];       // [800000]
    const float* ew = (const float*)d_in[4];     // [800000]
    float* out = (float*)d_out;                  // [50000, 128]

    // Workspace layout: x [50000*128 f32] then row_ptr [50001 i32]
    float* x = (float*)d_ws;
    int* row_ptr = (int*)((char*)d_ws + (size_t)N_NODES * OUT_FEAT * sizeof(float));

    gemm_rowptr_kernel<<<GEMM_BLOCKS + ROWPTR_BLOCKS, 128, 0, stream>>>(
        feat, weight, x, N_NODES, rows, row_ptr);
    spmm_kernel<<<(N_NODES + 3) / 4, 256, 0, stream>>>(x, cols, ew, row_ptr, out);
}